// Round 1
// baseline (10998.468 us; speedup 1.0000x reference)
//
#include <hip/hip_runtime.h>
#include <cstddef>

// Problem constants
constexpr int B   = 128;
constexpr int T   = 20;
constexpr int V   = 20000;
constexpr int DW  = 512;    // word dim
constexpr int DI  = 512;    // feat dim
constexpr int H   = 1024;   // lstm hidden
constexpr int G4  = 4096;   // 4*H
constexpr int NI  = 36;     // img regions
constexpr int NP  = 100;    // ppl regions
constexpr int KL  = 2560;   // lang concat K (512 attn + 1024 h_vis + 1024 h_lang)
constexpr int SOS = 1;

__device__ __forceinline__ float sigf(float x) { return 1.0f / (1.0f + expf(-x)); }

// ---------------------------------------------------------------------------
// Generic f32 GEMM: C[M,N] = A[M,K] @ op(B) (+Add[M,N]) (+bias[N])
// BT=true : B is [N,K] row-major with leading dim ldb (i.e. C = A @ B^T)
// BT=false: B is [K,N] row-major with leading dim ldb
// Requires M % 64 == 0, K % 16 == 0. N arbitrary (guarded).
// ---------------------------------------------------------------------------
template<bool BT, bool HAS_ADD, bool HAS_BIAS>
__global__ __launch_bounds__(256)
void gemm_f32(const float* __restrict__ A, const float* __restrict__ Bp,
              const float* __restrict__ Add, const float* __restrict__ bias,
              float* __restrict__ C, int M, int N, int K, int ldb)
{
    __shared__ float As[16][68];
    __shared__ float Bs[16][68];
    const int bm  = blockIdx.y * 64;
    const int bn  = blockIdx.x * 64;
    const int tid = threadIdx.x;
    const int tx  = tid & 15;   // n direction
    const int ty  = tid >> 4;   // m direction
    float acc[4][4] = {{0.f, 0.f, 0.f, 0.f}, {0.f, 0.f, 0.f, 0.f},
                       {0.f, 0.f, 0.f, 0.f}, {0.f, 0.f, 0.f, 0.f}};

    for (int k0 = 0; k0 < K; k0 += 16) {
        {   // A tile 64x16
            const int r = tid >> 2, c = (tid & 3) << 2;
            float4 av = *(const float4*)(A + (size_t)(bm + r) * K + k0 + c);
            As[c + 0][r] = av.x; As[c + 1][r] = av.y;
            As[c + 2][r] = av.z; As[c + 3][r] = av.w;
        }
        if constexpr (BT) {
            const int r = tid >> 2, c = (tid & 3) << 2;
            const int n = bn + r;
            float4 bv = make_float4(0.f, 0.f, 0.f, 0.f);
            if (n < N) bv = *(const float4*)(Bp + (size_t)n * ldb + k0 + c);
            Bs[c + 0][r] = bv.x; Bs[c + 1][r] = bv.y;
            Bs[c + 2][r] = bv.z; Bs[c + 3][r] = bv.w;
        } else {
            const int kk = tid >> 4, c = (tid & 15) << 2;
            const int n = bn + c;
            float4 bv;
            if (n + 3 < N) {
                bv = *(const float4*)(Bp + (size_t)(k0 + kk) * ldb + n);
            } else {
                bv.x = (n + 0 < N) ? Bp[(size_t)(k0 + kk) * ldb + n + 0] : 0.f;
                bv.y = (n + 1 < N) ? Bp[(size_t)(k0 + kk) * ldb + n + 1] : 0.f;
                bv.z = (n + 2 < N) ? Bp[(size_t)(k0 + kk) * ldb + n + 2] : 0.f;
                bv.w = (n + 3 < N) ? Bp[(size_t)(k0 + kk) * ldb + n + 3] : 0.f;
            }
            Bs[kk][c + 0] = bv.x; Bs[kk][c + 1] = bv.y;
            Bs[kk][c + 2] = bv.z; Bs[kk][c + 3] = bv.w;
        }
        __syncthreads();
#pragma unroll
        for (int k = 0; k < 16; ++k) {
            const float4 a = *(const float4*)&As[k][ty << 2];
            const float4 b = *(const float4*)&Bs[k][tx << 2];
            acc[0][0] += a.x * b.x; acc[0][1] += a.x * b.y; acc[0][2] += a.x * b.z; acc[0][3] += a.x * b.w;
            acc[1][0] += a.y * b.x; acc[1][1] += a.y * b.y; acc[1][2] += a.y * b.z; acc[1][3] += a.y * b.w;
            acc[2][0] += a.z * b.x; acc[2][1] += a.z * b.y; acc[2][2] += a.z * b.z; acc[2][3] += a.z * b.w;
            acc[3][0] += a.w * b.x; acc[3][1] += a.w * b.y; acc[3][2] += a.w * b.z; acc[3][3] += a.w * b.w;
        }
        __syncthreads();
    }
#pragma unroll
    for (int i = 0; i < 4; ++i) {
        const int m = bm + (ty << 2) + i;
#pragma unroll
        for (int j = 0; j < 4; ++j) {
            const int n = bn + (tx << 2) + j;
            if (n < N) {
                float v = acc[i][j];
                if constexpr (HAS_ADD)  v += Add[(size_t)m * N + n];
                if constexpr (HAS_BIAS) v += bias[n];
                C[(size_t)m * N + n] = v;
            }
        }
    }
}

// ---------------------------------------------------------------------------
// scores[b,n] = sum_h tanh(q[b*qld + h] + mW[(b*Nn+n)*Hd + h]) * v[h]
// grid (Nn, B), block 256
// ---------------------------------------------------------------------------
__global__ __launch_bounds__(256)
void attn_score(const float* __restrict__ q, int qld,
                const float* __restrict__ mW, const float* __restrict__ v,
                float* __restrict__ score, int Nn, int Hd)
{
    const int n = blockIdx.x, b = blockIdx.y;
    const float* qp = q + (size_t)b * qld;
    const float* mp = mW + ((size_t)b * Nn + n) * Hd;
    float s = 0.f;
    for (int h = threadIdx.x; h < Hd; h += 256)
        s += tanhf(qp[h] + mp[h]) * v[h];
    __shared__ float red[4];
    const int lane = threadIdx.x & 63, wv = threadIdx.x >> 6;
    for (int o = 32; o; o >>= 1) s += __shfl_down(s, o, 64);
    if (lane == 0) red[wv] = s;
    __syncthreads();
    if (threadIdx.x == 0) score[(size_t)b * Nn + n] = red[0] + red[1] + red[2] + red[3];
}

// ---------------------------------------------------------------------------
// softmax over n of score[b,:], then ctx[b, d] (=|+=) sum_n a[n]*m[b,n,d]
// one block per b, block 256
// ---------------------------------------------------------------------------
template<bool ACC>
__global__ __launch_bounds__(256)
void attn_ctx(const float* __restrict__ score, const float* __restrict__ m,
              float* __restrict__ ctx, int Nn, int D, int ldc)
{
    const int b = blockIdx.x;
    __shared__ float aw[128];
    __shared__ float red[8];
    const int tid = threadIdx.x, lane = tid & 63, wv = tid >> 6;

    float mx = -3.4e38f;
    for (int n = tid; n < Nn; n += 256) mx = fmaxf(mx, score[(size_t)b * Nn + n]);
    for (int o = 32; o; o >>= 1) mx = fmaxf(mx, __shfl_down(mx, o, 64));
    if (lane == 0) red[wv] = mx;
    __syncthreads();
    mx = fmaxf(fmaxf(red[0], red[1]), fmaxf(red[2], red[3]));

    float se = 0.f;
    for (int n = tid; n < Nn; n += 256) {
        float e = expf(score[(size_t)b * Nn + n] - mx);
        aw[n] = e;
        se += e;
    }
    for (int o = 32; o; o >>= 1) se += __shfl_down(se, o, 64);
    if (lane == 0) red[4 + wv] = se;
    __syncthreads();
    const float inv = 1.0f / (red[4] + red[5] + red[6] + red[7]);

    for (int d = tid; d < D; d += 256) {
        float s = 0.f;
        for (int n = 0; n < Nn; ++n)
            s += aw[n] * m[((size_t)b * Nn + n) * D + d];
        s *= inv;
        if constexpr (ACC) ctx[(size_t)b * ldc + d] += s;
        else               ctx[(size_t)b * ldc + d]  = s;
    }
}

// ---------------------------------------------------------------------------
// LSTM cell elementwise. gates [B,4096] (i,f,g,o), also packs h into x_cat slot
// grid B*H/256
// ---------------------------------------------------------------------------
__global__ __launch_bounds__(256)
void lstm_cell(const float* __restrict__ gates, const float* __restrict__ c_in,
               float* __restrict__ h_out, float* __restrict__ c_out,
               float* __restrict__ xslot)
{
    const int idx = blockIdx.x * 256 + threadIdx.x;
    const int b = idx >> 10, j = idx & 1023;
    const float* gp = gates + (size_t)b * G4;
    const float ig = gp[j], fg = gp[H + j], gg = gp[2 * H + j], og = gp[3 * H + j];
    const float c = sigf(fg) * c_in[idx] + sigf(ig) * tanhf(gg);
    const float h = sigf(og) * tanhf(c);
    c_out[idx] = c;
    h_out[idx] = h;
    xslot[(size_t)b * KL + j] = h;
}

// ---------------------------------------------------------------------------
// demb[(t*B+b), :] = relu(emb[tok_in(b,t), :])  — float4 over T*B*DW/4
// ---------------------------------------------------------------------------
__global__ __launch_bounds__(256)
void embed_relu(const int* __restrict__ question, const float* __restrict__ emb,
                float* __restrict__ demb)
{
    const int idx = blockIdx.x * 256 + threadIdx.x;   // T*B*128
    const int d4 = idx & 127;
    const int bt = idx >> 7;                          // t*B + b
    const int t = bt / B, b = bt - t * B;
    const int tok = (t == 0) ? SOS : question[b * T + t - 1];
    float4 e = *(const float4*)(emb + (size_t)tok * DW + (d4 << 2));
    e.x = fmaxf(e.x, 0.f); e.y = fmaxf(e.y, 0.f);
    e.z = fmaxf(e.z, 0.f); e.w = fmaxf(e.w, 0.f);
    *(float4*)(demb + (size_t)bt * DW + (d4 << 2)) = e;
}

// g_pre[t,b,:] += g_const[b,:]   (float4 over T*B*G4/4)
__global__ __launch_bounds__(256)
void add_bcast(float* __restrict__ g_pre, const float* __restrict__ g_const)
{
    const int idx = blockIdx.x * 256 + threadIdx.x;
    const int bg = idx % (B * G4 / 4);
    float4 a = ((float4*)g_pre)[idx];
    const float4 c = ((const float4*)g_const)[bg];
    a.x += c.x; a.y += c.y; a.z += c.z; a.w += c.w;
    ((float4*)g_pre)[idx] = a;
}

// Wcat[j, 0:1536] = lang_Wih[j,:], Wcat[j, 1536:2560] = lang_Whh[j,:]
__global__ __launch_bounds__(256)
void build_wcat(const float* __restrict__ Wih, const float* __restrict__ Whh,
                float* __restrict__ Wcat)
{
    const int idx = blockIdx.x * 256 + threadIdx.x;   // G4*KL
    const int j = idx / KL, k = idx - j * KL;
    Wcat[idx] = (k < 1536) ? Wih[(size_t)j * 1536 + k]
                           : Whh[(size_t)j * 1024 + (k - 1536)];
}

// Wqcat[k, 0:1024] = img_Wq[k,:], Wqcat[k, 1024:2048] = ppl_Wq[k,:]  ([K,N] layout)
__global__ __launch_bounds__(256)
void build_wqcat(const float* __restrict__ Wq1, const float* __restrict__ Wq2,
                 float* __restrict__ Wqcat)
{
    const int idx = blockIdx.x * 256 + threadIdx.x;   // H*2048
    const int k = idx >> 11, n = idx & 2047;
    Wqcat[idx] = (n < 1024) ? Wq1[(size_t)k * 1024 + n]
                            : Wq2[(size_t)k * 1024 + (n - 1024)];
}

__global__ __launch_bounds__(256)
void zero_f(float* __restrict__ p, int n)
{
    const int i = blockIdx.x * 256 + threadIdx.x;
    if (i < n) p[i] = 0.f;
}

// ---------------------------------------------------------------------------
// log_softmax of logits[b,:] -> out[(b*T+t)*V + :], argmax -> out[B*T*V + b*T+t]
// one block per b
// ---------------------------------------------------------------------------
__global__ __launch_bounds__(256)
void logsm_argmax(const float* __restrict__ logits, float* __restrict__ out, int t)
{
    const int b = blockIdx.x;
    const float* row = logits + (size_t)b * V;
    const int tid = threadIdx.x, lane = tid & 63, wv = tid >> 6;
    __shared__ float rmax[4];
    __shared__ int   ridx[4];
    __shared__ float rsum[4];

    float mx = -3.4e38f; int mi = 0;
    for (int n = tid; n < V; n += 256) {
        const float x = row[n];
        if (x > mx) { mx = x; mi = n; }
    }
    for (int o = 32; o; o >>= 1) {
        const float om = __shfl_down(mx, o, 64);
        const int   oi = __shfl_down(mi, o, 64);
        if (om > mx || (om == mx && oi < mi)) { mx = om; mi = oi; }
    }
    if (lane == 0) { rmax[wv] = mx; ridx[wv] = mi; }
    __syncthreads();
    mx = rmax[0]; mi = ridx[0];
    for (int w = 1; w < 4; ++w)
        if (rmax[w] > mx || (rmax[w] == mx && ridx[w] < mi)) { mx = rmax[w]; mi = ridx[w]; }

    float se = 0.f;
    for (int n = tid; n < V; n += 256) se += expf(row[n] - mx);
    for (int o = 32; o; o >>= 1) se += __shfl_down(se, o, 64);
    if (lane == 0) rsum[wv] = se;
    __syncthreads();
    const float lse = mx + logf(rsum[0] + rsum[1] + rsum[2] + rsum[3]);

    float* dst = out + ((size_t)b * T + t) * V;
    for (int n = tid; n < V; n += 256) dst[n] = row[n] - lse;
    if (tid == 0) out[(size_t)B * T * V + b * T + t] = (float)mi;
}

// ---------------------------------------------------------------------------
extern "C" void kernel_launch(void* const* d_in, const int* in_sizes, int n_in,
                              void* d_out, int out_size, void* d_ws, size_t ws_size,
                              hipStream_t stream)
{
    (void)in_sizes; (void)n_in; (void)out_size; (void)ws_size;

    const float* img_feats   = (const float*)d_in[0];
    const float* ppl_feats   = (const float*)d_in[1];
    const float* answer_hint = (const float*)d_in[2];
    const int*   question    = (const int*)d_in[3];
    const float* emb         = (const float*)d_in[4];
    const float* pool_Wq     = (const float*)d_in[5];
    const float* pool_Wm     = (const float*)d_in[6];
    const float* pool_b      = (const float*)d_in[7];
    const float* pool_v      = (const float*)d_in[8];
    const float* img_Wq      = (const float*)d_in[9];
    const float* img_Wm      = (const float*)d_in[10];
    const float* img_b       = (const float*)d_in[11];
    const float* img_v       = (const float*)d_in[12];
    const float* ppl_Wq      = (const float*)d_in[13];
    const float* ppl_Wm      = (const float*)d_in[14];
    const float* ppl_b       = (const float*)d_in[15];
    const float* ppl_v       = (const float*)d_in[16];
    const float* vis_Wih     = (const float*)d_in[17];
    const float* vis_Whh     = (const float*)d_in[18];
    const float* vis_b       = (const float*)d_in[19];
    const float* lang_Wih    = (const float*)d_in[20];
    const float* lang_Whh    = (const float*)d_in[21];
    const float* lang_b      = (const float*)d_in[22];
    const float* proj_W      = (const float*)d_in[23];
    const float* proj_b      = (const float*)d_in[24];

    float* out = (float*)d_out;
    float* ws  = (float*)d_ws;

    // workspace layout (floats, 64-float aligned)
    size_t off = 0;
    auto alloc = [&](size_t nf) { size_t r = off; off += (nf + 63) & ~(size_t)63; return r; };
    float* img_mW   = ws + alloc((size_t)B * NI * H);     // 4608 x 1024
    float* ppl_mW   = ws + alloc((size_t)B * NP * H);     // 12800 x 1024
    float* demb     = ws + alloc((size_t)T * B * DW);     // 2560 x 512
    float* g_pre    = ws + alloc((size_t)T * B * G4);     // 20 x 128 x 4096
    float* wcat     = ws + alloc((size_t)G4 * KL);        // 4096 x 2560
    float* wqcat    = ws + alloc((size_t)H * 2048);       // 1024 x 2048
    float* pool_qW  = ws + alloc((size_t)B * DW);
    float* pool_mW  = ws + alloc((size_t)B * NI * DW);    // 4608 x 512
    float* pool_sc  = ws + alloc((size_t)B * NI);
    float* img_pool = ws + alloc((size_t)B * DW);
    float* g_const  = ws + alloc((size_t)B * G4);
    float* h_vis    = ws + alloc((size_t)B * H);          // states: keep contiguous
    float* c_vis    = ws + alloc((size_t)B * H);
    float* h_lang   = ws + alloc((size_t)B * H);
    float* c_lang   = ws + alloc((size_t)B * H);
    float* x_cat    = ws + alloc((size_t)B * KL);
    float* gates    = ws + alloc((size_t)B * G4);
    float* qbuf     = ws + alloc((size_t)B * 2048);
    float* score    = ws + alloc((size_t)B * NP);
    float* logits   = ws + alloc((size_t)B * V);

    const dim3 blk(256);
    auto grid2 = [](int M, int N) { return dim3((unsigned)((N + 63) / 64), (unsigned)(M / 64)); };

    // ---- precompute ----
    // zero h_vis, c_vis, h_lang, c_lang, x_cat (contiguous: 4*B*H + B*KL floats)
    {
        const int nz = 4 * B * H + B * KL;   // 851968
        zero_f<<<dim3((nz + 255) / 256), blk, 0, stream>>>(h_vis, nz);
    }
    embed_relu<<<dim3(T * B * DW / 4 / 256), blk, 0, stream>>>(question, emb, demb);
    // g_pre = demb @ vis_Wih[:,512:]^T + vis_b
    gemm_f32<true, false, true><<<grid2(T * B, G4), blk, 0, stream>>>(
        demb, vis_Wih + 512, nullptr, vis_b, g_pre, T * B, G4, DW, H);
    // pool attention -> img_pool
    gemm_f32<false, false, false><<<grid2(B, DW), blk, 0, stream>>>(
        answer_hint, pool_Wq, nullptr, nullptr, pool_qW, B, DW, DW, DW);
    gemm_f32<false, false, true><<<grid2(B * NI, DW), blk, 0, stream>>>(
        img_feats, pool_Wm, nullptr, pool_b, pool_mW, B * NI, DW, DI, DW);
    attn_score<<<dim3(NI, B), blk, 0, stream>>>(pool_qW, DW, pool_mW, pool_v, pool_sc, NI, DW);
    attn_ctx<false><<<dim3(B), blk, 0, stream>>>(pool_sc, img_feats, img_pool, NI, DI, DI);
    // g_const = img_pool @ vis_Wih[:,:512]^T ; broadcast-add into g_pre
    gemm_f32<true, false, false><<<grid2(B, G4), blk, 0, stream>>>(
        img_pool, vis_Wih, nullptr, nullptr, g_const, B, G4, DW, H);
    add_bcast<<<dim3(T * B * G4 / 4 / 256), blk, 0, stream>>>(g_pre, g_const);
    // attention memory projections (+ bias folded in)
    gemm_f32<false, false, true><<<grid2(B * NI, H), blk, 0, stream>>>(
        img_feats, img_Wm, nullptr, img_b, img_mW, B * NI, H, DI, H);
    gemm_f32<false, false, true><<<grid2(B * NP, H), blk, 0, stream>>>(
        ppl_feats, ppl_Wm, nullptr, ppl_b, ppl_mW, B * NP, H, DI, H);
    // merged weights
    build_wcat<<<dim3(G4 * KL / 256), blk, 0, stream>>>(lang_Wih, lang_Whh, wcat);
    build_wqcat<<<dim3(H * 2048 / 256), blk, 0, stream>>>(img_Wq, ppl_Wq, wqcat);

    // ---- sequential decode ----
    for (int t = 0; t < T; ++t) {
        // vis gates = h_vis @ vis_Whh^T + g_pre[t]
        gemm_f32<true, true, false><<<grid2(B, G4), blk, 0, stream>>>(
            h_vis, vis_Whh, g_pre + (size_t)t * B * G4, nullptr, gates, B, G4, H, H);
        lstm_cell<<<dim3(B * H / 256), blk, 0, stream>>>(gates, c_vis, h_vis, c_vis, x_cat + 512);
        // q for both attentions: [128,1024] @ [1024,2048]
        gemm_f32<false, false, false><<<grid2(B, 2048), blk, 0, stream>>>(
            h_vis, wqcat, nullptr, nullptr, qbuf, B, 2048, H, 2048);
        attn_score<<<dim3(NI, B), blk, 0, stream>>>(qbuf, 2048, img_mW, img_v, score, NI, H);
        attn_ctx<false><<<dim3(B), blk, 0, stream>>>(score, img_feats, x_cat, NI, DI, KL);
        attn_score<<<dim3(NP, B), blk, 0, stream>>>(qbuf + 1024, 2048, ppl_mW, ppl_v, score, NP, H);
        attn_ctx<true><<<dim3(B), blk, 0, stream>>>(score, ppl_feats, x_cat, NP, DI, KL);
        // lang gates = x_cat @ wcat^T + lang_b   (x_cat = [attn, h_vis, h_lang_prev])
        gemm_f32<true, false, true><<<grid2(B, G4), blk, 0, stream>>>(
            x_cat, wcat, nullptr, lang_b, gates, B, G4, KL, KL);
        lstm_cell<<<dim3(B * H / 256), blk, 0, stream>>>(gates, c_lang, h_lang, c_lang, x_cat + 1536);
        // logits = h_lang @ proj_W + proj_b
        gemm_f32<false, false, true><<<grid2(B, V), blk, 0, stream>>>(
            h_lang, proj_W, nullptr, proj_b, logits, B, V, H, V);
        logsm_argmax<<<dim3(B), blk, 0, stream>>>(logits, out, t);
    }
}

// Round 2
// 5247.821 us; speedup vs baseline: 2.0958x; 2.0958x over previous
//
#include <hip/hip_runtime.h>
#include <cstddef>
#include <cstdint>

using u16 = unsigned short;
typedef float    f32x4 __attribute__((ext_vector_type(4)));
typedef _Float16 f16x8 __attribute__((ext_vector_type(8)));
typedef u16      us8   __attribute__((ext_vector_type(8)));

constexpr int B  = 128;
constexpr int T  = 20;
constexpr int V  = 20000;
constexpr int DW = 512;
constexpr int DI = 512;
constexpr int H  = 1024;
constexpr int G4 = 4096;
constexpr int NI = 36;
constexpr int NP = 100;
constexpr int KL = 2560;   // lang concat K: 512 attn + 1024 h_vis + 1024 h_lang
constexpr int SOS = 1;

__device__ __forceinline__ float sigf(float x) { return 1.0f / (1.0f + expf(-x)); }
__device__ __forceinline__ u16 f16bits(_Float16 h) { u16 u; __builtin_memcpy(&u, &h, 2); return u; }

// f16x3 split: x ~= hi + lo, stored as triples so that a single K-expanded f16
// GEMM computes hi*hi + lo*hi + hi*lo (error ~2^-22 per product).
// A-side triple: [hi, lo*64, hi/64];  W-side triple: [hi, hi/64, lo*64]
template<bool WSIDE>
__device__ __forceinline__ void split1(float x, u16& b0, u16& b1, u16& b2) {
    _Float16 h  = (_Float16)x;
    float    hf = (float)h;
    _Float16 lo = (_Float16)((x - hf) * 64.0f);
    _Float16 hs = (_Float16)(hf * (1.0f / 64.0f));
    b0 = f16bits(h);
    if constexpr (WSIDE) { b1 = f16bits(hs); b2 = f16bits(lo); }
    else                 { b1 = f16bits(lo); b2 = f16bits(hs); }
}

// ---------------------------------------------------------------------------
// MFMA GEMM: C[M,N] = A3[M,K3] x B3t[N,K3]^T (+Add) (+bias), f16 inputs f32 out.
// Both operands K-contiguous (B pre-transposed). BK=64, 256 threads, 4 waves
// in 2x2, each wave (BM/2)x(BN/2) via 16x16x32 fragments. LDS XOR-swizzled
// (byte ^= (row&7)<<4) on both ds_write and ds_read -> conflict-free b128.
// M must be divisible by BM; N arbitrary (B-row clamp + C-col guard).
// ---------------------------------------------------------------------------
template<int BM, int BN, bool HAS_ADD, bool HAS_BIAS>
__global__ __launch_bounds__(256)
void gemm3(const u16* __restrict__ A, const u16* __restrict__ Bt,
           const float* __restrict__ Add, const float* __restrict__ bias,
           float* __restrict__ C, int N, int K3)
{
    __shared__ __align__(16) u16 As[BM * 64];
    __shared__ __align__(16) u16 Bs[BN * 64];
    constexpr int FR = BM / 32, FC = BN / 32, PA = BM / 32, PB = BN / 32;
    const int tid  = threadIdx.x;
    const int bm   = blockIdx.y * BM, bn = blockIdx.x * BN;
    const int lane = tid & 63, wid = tid >> 6;
    const int wm   = (wid >> 1) * (BM / 2), wn = (wid & 1) * (BN / 2);
    const int srow = tid >> 3;           // 32 rows per staging pass
    const int scol = (tid & 7) * 8;      // 8 f16 = 16B per thread

    f32x4 acc[FR][FC] = {};

    for (int k0 = 0; k0 < K3; k0 += 64) {
        us8 ra[PA], rb[PB];
#pragma unroll
        for (int p = 0; p < PA; ++p) {
            const int row = p * 32 + srow;
            ra[p] = *(const us8*)(A + (size_t)(bm + row) * K3 + k0 + scol);
        }
#pragma unroll
        for (int p = 0; p < PB; ++p) {
            const int row = p * 32 + srow;
            int n = bn + row; if (n > N - 1) n = N - 1;   // clamp (masked at C-write)
            rb[p] = *(const us8*)(Bt + (size_t)n * K3 + k0 + scol);
        }
        __syncthreads();   // previous tile's compute done
#pragma unroll
        for (int p = 0; p < PA; ++p) {
            const int row = p * 32 + srow;
            *(us8*)((char*)As + row * 128 + ((scol * 2) ^ ((row & 7) << 4))) = ra[p];
        }
#pragma unroll
        for (int p = 0; p < PB; ++p) {
            const int row = p * 32 + srow;
            *(us8*)((char*)Bs + row * 128 + ((scol * 2) ^ ((row & 7) << 4))) = rb[p];
        }
        __syncthreads();
#pragma unroll
        for (int ks = 0; ks < 2; ++ks) {
            f16x8 af[FR], bf[FC];
#pragma unroll
            for (int m = 0; m < FR; ++m) {
                const int row = wm + m * 16 + (lane & 15);
                const int cb  = (ks * 64 + ((lane >> 4) << 4)) ^ ((row & 7) << 4);
                af[m] = *(const f16x8*)((const char*)As + row * 128 + cb);
            }
#pragma unroll
            for (int n = 0; n < FC; ++n) {
                const int row = wn + n * 16 + (lane & 15);
                const int cb  = (ks * 64 + ((lane >> 4) << 4)) ^ ((row & 7) << 4);
                bf[n] = *(const f16x8*)((const char*)Bs + row * 128 + cb);
            }
#pragma unroll
            for (int m = 0; m < FR; ++m)
#pragma unroll
                for (int n = 0; n < FC; ++n)
                    acc[m][n] = __builtin_amdgcn_mfma_f32_16x16x32_f16(af[m], bf[n], acc[m][n], 0, 0, 0);
        }
    }
    // epilogue: C/D layout col = lane&15, row = (lane>>4)*4 + j
#pragma unroll
    for (int m = 0; m < FR; ++m) {
        const int r0 = bm + wm + m * 16 + ((lane >> 4) << 2);
#pragma unroll
        for (int n = 0; n < FC; ++n) {
            const int c = bn + wn + n * 16 + (lane & 15);
            if (c < N) {
#pragma unroll
                for (int j = 0; j < 4; ++j) {
                    float v = acc[m][n][j];
                    if constexpr (HAS_ADD)  v += Add[(size_t)(r0 + j) * N + c];
                    if constexpr (HAS_BIAS) v += bias[c];
                    C[(size_t)(r0 + j) * N + c] = v;
                }
            }
        }
    }
}

// ---------------------------------------------------------------------------
// Row-major source split: src f32 [M][ld] (Ksrc cols used) -> out triple at
// out[r][coloff + k], [Kt + coloff + k], [2Kt + coloff + k], out ld = 3*Kt.
// grid = M*Ksrc/8/256 exactly.
// ---------------------------------------------------------------------------
template<bool WSIDE>
__global__ __launch_bounds__(256)
void split3_rows(const float* __restrict__ src, int ld, int K8,
                 u16* __restrict__ out, int Kt, int coloff)
{
    const int idx = blockIdx.x * 256 + threadIdx.x;
    const int r = idx / K8, kk = (idx - r * K8) * 8;
    const float* s = src + (size_t)r * ld + kk;
    const float4 x0 = *(const float4*)s, x1 = *(const float4*)(s + 4);
    float xs[8] = {x0.x, x0.y, x0.z, x0.w, x1.x, x1.y, x1.z, x1.w};
    us8 h, m, l;
#pragma unroll
    for (int j = 0; j < 8; ++j) { u16 a, b, c; split1<WSIDE>(xs[j], a, b, c); h[j]=a; m[j]=b; l[j]=c; }
    u16* o = out + (size_t)r * (3 * Kt) + coloff + kk;
    *(us8*)o = h; *(us8*)(o + Kt) = m; *(us8*)(o + 2 * Kt) = l;
}

// ---------------------------------------------------------------------------
// Transpose + W-side split: W f32 [K][N] -> out u16 [N][3K].
// grid (ceil(N/64), K/64), 256 threads, LDS-tiled.
// ---------------------------------------------------------------------------
__global__ __launch_bounds__(256)
void transpose_split3_w(const float* __restrict__ W, int N, int K,
                        u16* __restrict__ out)
{
    const int n0 = blockIdx.x * 64, k0 = blockIdx.y * 64;
    const int tid = threadIdx.x;
    __shared__ float ts[64][65];
    for (int i = 0; i < 16; ++i) {
        const int idx = i * 256 + tid;
        const int kl = idx >> 6, nl = idx & 63;
        float v = 0.f;
        if (n0 + nl < N) v = W[(size_t)(k0 + kl) * N + n0 + nl];
        ts[nl][kl] = v;
    }
    __syncthreads();
    for (int i = 0; i < 2; ++i) {
        const int idx = i * 256 + tid;
        const int nl = idx >> 3, kc = (idx & 7) * 8;
        if (n0 + nl < N) {
            us8 h, m, l;
#pragma unroll
            for (int j = 0; j < 8; ++j) {
                u16 a, b, c; split1<true>(ts[nl][kc + j], a, b, c);
                h[j] = a; m[j] = b; l[j] = c;
            }
            u16* o = out + (size_t)(n0 + nl) * (3 * K) + k0 + kc;
            *(us8*)o = h; *(us8*)(o + K) = m; *(us8*)(o + 2 * K) = l;
        }
    }
}

// embedding lookup + relu + A-side split -> demb3 [T*B][1536]
__global__ __launch_bounds__(256)
void embed_relu3(const int* __restrict__ question, const float* __restrict__ emb,
                 u16* __restrict__ demb3)
{
    const int idx = blockIdx.x * 256 + threadIdx.x;   // T*B*64
    const int r = idx >> 6, kk = (idx & 63) * 8;      // r = t*B + b
    const int t = r / B, b = r - t * B;
    const int tok = (t == 0) ? SOS : question[b * T + t - 1];
    const float* s = emb + (size_t)tok * DW + kk;
    const float4 x0 = *(const float4*)s, x1 = *(const float4*)(s + 4);
    float xs[8] = {x0.x, x0.y, x0.z, x0.w, x1.x, x1.y, x1.z, x1.w};
    us8 h, m, l;
#pragma unroll
    for (int j = 0; j < 8; ++j) {
        u16 a, b2, c; split1<false>(fmaxf(xs[j], 0.f), a, b2, c);
        h[j] = a; m[j] = b2; l[j] = c;
    }
    u16* o = demb3 + (size_t)r * 1536 + kk;
    *(us8*)o = h; *(us8*)(o + 512) = m; *(us8*)(o + 1024) = l;
}

// scores[b,n] = sum_h tanh(q[b,h] + mW[b,n,h]) * v[h]
__global__ __launch_bounds__(256)
void attn_score(const float* __restrict__ q, int qld,
                const float* __restrict__ mW, const float* __restrict__ v,
                float* __restrict__ score, int Nn, int Hd)
{
    const int n = blockIdx.x, b = blockIdx.y;
    const float* qp = q + (size_t)b * qld;
    const float* mp = mW + ((size_t)b * Nn + n) * Hd;
    float s = 0.f;
    for (int h = threadIdx.x; h < Hd; h += 256)
        s += tanhf(qp[h] + mp[h]) * v[h];
    __shared__ float red[4];
    const int lane = threadIdx.x & 63, wv = threadIdx.x >> 6;
    for (int o = 32; o; o >>= 1) s += __shfl_down(s, o, 64);
    if (lane == 0) red[wv] = s;
    __syncthreads();
    if (threadIdx.x == 0) score[(size_t)b * Nn + n] = red[0] + red[1] + red[2] + red[3];
}

// softmax(score) -> context. MODE 0: pool -> img_pool3 triple (Kt=512)
// MODE 1: img -> attn_buf f32 ; MODE 2: ppl: attn_buf + ctx -> x3 triple (Kt=2560)
template<int MODE>
__global__ __launch_bounds__(256)
void attn_ctx(const float* __restrict__ score, const float* __restrict__ m,
              float* __restrict__ fbuf, u16* __restrict__ out3, int Nn)
{
    constexpr int D = 512;
    const int b = blockIdx.x;
    __shared__ float aw[128];
    __shared__ float red[8];
    const int tid = threadIdx.x, lane = tid & 63, wv = tid >> 6;

    float mx = -3.4e38f;
    for (int n = tid; n < Nn; n += 256) mx = fmaxf(mx, score[(size_t)b * Nn + n]);
    for (int o = 32; o; o >>= 1) mx = fmaxf(mx, __shfl_down(mx, o, 64));
    if (lane == 0) red[wv] = mx;
    __syncthreads();
    mx = fmaxf(fmaxf(red[0], red[1]), fmaxf(red[2], red[3]));

    float se = 0.f;
    for (int n = tid; n < Nn; n += 256) {
        float e = expf(score[(size_t)b * Nn + n] - mx);
        aw[n] = e; se += e;
    }
    for (int o = 32; o; o >>= 1) se += __shfl_down(se, o, 64);
    if (lane == 0) red[4 + wv] = se;
    __syncthreads();
    const float inv = 1.0f / (red[4] + red[5] + red[6] + red[7]);

    for (int d = tid; d < D; d += 256) {
        float s = 0.f;
        for (int n = 0; n < Nn; ++n) s += aw[n] * m[((size_t)b * Nn + n) * D + d];
        s *= inv;
        if constexpr (MODE == 1) {
            fbuf[(size_t)b * D + d] = s;
        } else {
            if constexpr (MODE == 2) s += fbuf[(size_t)b * D + d];
            constexpr int Kt = (MODE == 0) ? 512 : 2560;
            u16 b0, b1, b2; split1<false>(s, b0, b1, b2);
            u16* o = out3 + (size_t)b * 3 * Kt + d;
            o[0] = b0; o[Kt] = b1; o[2 * Kt] = b2;
        }
    }
}

// vis LSTM cell: gates[B,4096] (i,f,g,o) -> c, h-splits into a3 + x3(h_vis slot)
__global__ __launch_bounds__(256)
void lstm_vis(const float* __restrict__ gates, float* __restrict__ c_st,
              u16* __restrict__ a3, u16* __restrict__ x3)
{
    const int idx = blockIdx.x * 256 + threadIdx.x;
    const int b = idx >> 10, j = idx & 1023;
    const float* gp = gates + (size_t)b * G4;
    const float c = sigf(gp[H + j]) * c_st[idx] + sigf(gp[j]) * tanhf(gp[2 * H + j]);
    const float h = sigf(gp[3 * H + j]) * tanhf(c);
    c_st[idx] = c;
    u16 b0, b1, b2; split1<false>(h, b0, b1, b2);
    a3[(size_t)b * 3072 + j]        = b0;
    a3[(size_t)b * 3072 + 1024 + j] = b1;
    a3[(size_t)b * 3072 + 2048 + j] = b2;
    x3[(size_t)b * 7680 + 512 + j]  = b0;   // slot 512+j -> {.., +2560, +5120}
    x3[(size_t)b * 7680 + 3072 + j] = b1;
    x3[(size_t)b * 7680 + 5632 + j] = b2;
}

// lang LSTM cell: -> c, h-splits into x3(h_lang slot) + h3_all row (b*T+t)
__global__ __launch_bounds__(256)
void lstm_lang(const float* __restrict__ gates, float* __restrict__ c_st,
               u16* __restrict__ x3, u16* __restrict__ h3, int t)
{
    const int idx = blockIdx.x * 256 + threadIdx.x;
    const int b = idx >> 10, j = idx & 1023;
    const float* gp = gates + (size_t)b * G4;
    const float c = sigf(gp[H + j]) * c_st[idx] + sigf(gp[j]) * tanhf(gp[2 * H + j]);
    const float h = sigf(gp[3 * H + j]) * tanhf(c);
    c_st[idx] = c;
    u16 b0, b1, b2; split1<false>(h, b0, b1, b2);
    x3[(size_t)b * 7680 + 1536 + j] = b0;
    x3[(size_t)b * 7680 + 4096 + j] = b1;
    x3[(size_t)b * 7680 + 6656 + j] = b2;
    u16* o = h3 + ((size_t)b * T + t) * 3072 + j;
    o[0] = b0; o[1024] = b1; o[2048] = b2;
}

// g_pre[t,b,:] += g_const[b,:]
__global__ __launch_bounds__(256)
void add_bcast(float* __restrict__ g_pre, const float* __restrict__ g_const)
{
    const int idx = blockIdx.x * 256 + threadIdx.x;
    const int bg = idx % (B * G4 / 4);
    float4 a = ((float4*)g_pre)[idx];
    const float4 c = ((const float4*)g_const)[bg];
    a.x += c.x; a.y += c.y; a.z += c.z; a.w += c.w;
    ((float4*)g_pre)[idx] = a;
}

__global__ __launch_bounds__(256)
void zero_f(float* __restrict__ p) { p[blockIdx.x * 256 + threadIdx.x] = 0.f; }

__global__ __launch_bounds__(256)
void zero_u32(unsigned int* __restrict__ p) { p[blockIdx.x * 256 + threadIdx.x] = 0u; }

// batched in-place log_softmax over out rows [r][V], argmax -> out[BTV + r]
__global__ __launch_bounds__(256)
void logsm_argmax(float* __restrict__ out)
{
    const int r = blockIdx.x;
    float* row = out + (size_t)r * V;
    const int tid = threadIdx.x, lane = tid & 63, wv = tid >> 6;
    __shared__ float rmax[4];
    __shared__ int   ridx[4];
    __shared__ float rsum[4];

    float mx = -3.4e38f; int mi = 0;
    for (int n = tid; n < V; n += 256) {
        const float x = row[n];
        if (x > mx) { mx = x; mi = n; }
    }
    for (int o = 32; o; o >>= 1) {
        const float om = __shfl_down(mx, o, 64);
        const int   oi = __shfl_down(mi, o, 64);
        if (om > mx || (om == mx && oi < mi)) { mx = om; mi = oi; }
    }
    if (lane == 0) { rmax[wv] = mx; ridx[wv] = mi; }
    __syncthreads();
    mx = rmax[0]; mi = ridx[0];
    for (int w = 1; w < 4; ++w)
        if (rmax[w] > mx || (rmax[w] == mx && ridx[w] < mi)) { mx = rmax[w]; mi = ridx[w]; }

    float se = 0.f;
    for (int n = tid; n < V; n += 256) se += expf(row[n] - mx);
    for (int o = 32; o; o >>= 1) se += __shfl_down(se, o, 64);
    if (lane == 0) rsum[wv] = se;
    __syncthreads();
    const float lse = mx + logf(rsum[0] + rsum[1] + rsum[2] + rsum[3]);

    for (int n = tid; n < V; n += 256) row[n] -= lse;
    if (tid == 0) out[(size_t)B * T * V + r] = (float)mi;
}

// ---------------------------------------------------------------------------
extern "C" void kernel_launch(void* const* d_in, const int* in_sizes, int n_in,
                              void* d_out, int out_size, void* d_ws, size_t ws_size,
                              hipStream_t stream)
{
    (void)in_sizes; (void)n_in; (void)out_size; (void)ws_size;

    const float* img_feats   = (const float*)d_in[0];
    const float* ppl_feats   = (const float*)d_in[1];
    const float* answer_hint = (const float*)d_in[2];
    const int*   question    = (const int*)d_in[3];
    const float* emb         = (const float*)d_in[4];
    const float* pool_Wq     = (const float*)d_in[5];
    const float* pool_Wm     = (const float*)d_in[6];
    const float* pool_b      = (const float*)d_in[7];
    // pool_v d_in[8]
    const float* pool_v      = (const float*)d_in[8];
    const float* img_Wq      = (const float*)d_in[9];
    const float* img_Wm      = (const float*)d_in[10];
    const float* img_b       = (const float*)d_in[11];
    const float* img_v       = (const float*)d_in[12];
    const float* ppl_Wq      = (const float*)d_in[13];
    const float* ppl_Wm      = (const float*)d_in[14];
    const float* ppl_b       = (const float*)d_in[15];
    const float* ppl_v       = (const float*)d_in[16];
    const float* vis_Wih     = (const float*)d_in[17];   // [4096][1024]: cols 0-511 img_pool, 512-1023 demb
    const float* vis_Whh     = (const float*)d_in[18];   // [4096][1024]
    const float* vis_b       = (const float*)d_in[19];
    const float* lang_Wih    = (const float*)d_in[20];   // [4096][1536]
    const float* lang_Whh    = (const float*)d_in[21];   // [4096][1024]
    const float* lang_b      = (const float*)d_in[22];
    const float* proj_W      = (const float*)d_in[23];   // [1024][20000]
    const float* proj_b      = (const float*)d_in[24];

    float* out = (float*)d_out;
    float* ws  = (float*)d_ws;

    // ---- workspace layout (float units, 64-float aligned) ----
    size_t off = 0;
    auto alloc = [&](size_t nf) { size_t r = off; off += (nf + 63) & ~(size_t)63; return r; };
    // Region X: dead after the decode loop; projW3t is overlaid here post-loop.
    const size_t regionX = off;
    float* g_pre   = ws + alloc((size_t)T * B * G4);         // 10.49M f
    float* pool_mW = ws + alloc((size_t)B * NI * DW);        //  2.36M f
    float* img_mW  = ws + alloc((size_t)B * NI * H);         //  4.72M f
    float* ppl_mW  = ws + alloc((size_t)B * NP * H);         // 13.11M f
    u16*   demb3   = (u16*)(ws + alloc((size_t)T * B * 1536 / 2));   // 1.97M f
    // persistent
    u16* img3      = (u16*)(ws + alloc((size_t)B * NI * 1536 / 2));
    u16* ppl3      = (u16*)(ws + alloc((size_t)B * NP * 1536 / 2));
    u16* hint3     = (u16*)(ws + alloc((size_t)B * 1536 / 2));
    u16* imgpool3  = (u16*)(ws + alloc((size_t)B * 1536 / 2));
    u16* visdemb3  = (u16*)(ws + alloc((size_t)G4 * 1536 / 2));
    u16* vispool3  = (u16*)(ws + alloc((size_t)G4 * 1536 / 2));
    u16* visWhh3   = (u16*)(ws + alloc((size_t)G4 * 3072 / 2));
    u16* langW3    = (u16*)(ws + alloc((size_t)G4 * 7680 / 2));
    u16* wq3t      = (u16*)(ws + alloc((size_t)2048 * 3072 / 2));
    u16* poolWq3t  = (u16*)(ws + alloc((size_t)512 * 1536 / 2));
    u16* poolWm3t  = (u16*)(ws + alloc((size_t)512 * 1536 / 2));
    u16* imgWm3t   = (u16*)(ws + alloc((size_t)1024 * 1536 / 2));
    u16* pplWm3t   = (u16*)(ws + alloc((size_t)1024 * 1536 / 2));
    u16* a3        = (u16*)(ws + alloc((size_t)B * 3072 / 2));   // a3 + x3 adjacent (zeroed together)
    u16* x3        = (u16*)(ws + alloc((size_t)B * 7680 / 2));
    u16* h3_all    = (u16*)(ws + alloc((size_t)B * T * 3072 / 2));
    float* c_vis   = ws + alloc((size_t)B * H);                  // c_vis + c_lang adjacent
    float* c_lang  = ws + alloc((size_t)B * H);
    float* attn_buf= ws + alloc((size_t)B * DW);
    float* qbuf    = ws + alloc((size_t)B * 2048);
    float* gates   = ws + alloc((size_t)B * G4);
    float* g_const = ws + alloc((size_t)B * G4);
    float* pool_qW = ws + alloc((size_t)B * DW);
    float* score   = ws + alloc((size_t)B * NP);
    float* pool_sc = ws + alloc((size_t)B * NI);
    u16* projW3t   = (u16*)(ws + regionX);                       // overlay, built post-loop

    const dim3 blk(256);

    // ---- init state ----
    zero_f<<<dim3((2 * B * H) / 256), blk, 0, stream>>>(c_vis);                    // c_vis, c_lang
    zero_u32<<<dim3((B * 3072 + B * 7680) / 2 / 256), blk, 0, stream>>>((unsigned int*)a3);  // a3, x3

    // ---- one-time splits / transposes ----
    embed_relu3<<<dim3(T * B * 64 / 256), blk, 0, stream>>>(question, emb, demb3);
    split3_rows<true><<<dim3(G4 * 64 / 256), blk, 0, stream>>>(vis_Wih + 512, 1024, 64, visdemb3, 512, 0);
    split3_rows<true><<<dim3(G4 * 64 / 256), blk, 0, stream>>>(vis_Wih, 1024, 64, vispool3, 512, 0);
    split3_rows<true><<<dim3(G4 * 128 / 256), blk, 0, stream>>>(vis_Whh, 1024, 128, visWhh3, 1024, 0);
    split3_rows<true><<<dim3(G4 * 192 / 256), blk, 0, stream>>>(lang_Wih, 1536, 192, langW3, 2560, 0);
    split3_rows<true><<<dim3(G4 * 128 / 256), blk, 0, stream>>>(lang_Whh, 1024, 128, langW3, 2560, 1536);
    split3_rows<false><<<dim3(B * NI * 64 / 256), blk, 0, stream>>>(img_feats, 512, 64, img3, 512, 0);
    split3_rows<false><<<dim3(B * NP * 64 / 256), blk, 0, stream>>>(ppl_feats, 512, 64, ppl3, 512, 0);
    split3_rows<false><<<dim3(B * 64 / 256), blk, 0, stream>>>(answer_hint, 512, 64, hint3, 512, 0);
    transpose_split3_w<<<dim3(8, 8), blk, 0, stream>>>(pool_Wq, 512, 512, poolWq3t);
    transpose_split3_w<<<dim3(8, 8), blk, 0, stream>>>(pool_Wm, 512, 512, poolWm3t);
    transpose_split3_w<<<dim3(16, 8), blk, 0, stream>>>(img_Wm, 1024, 512, imgWm3t);
    transpose_split3_w<<<dim3(16, 8), blk, 0, stream>>>(ppl_Wm, 1024, 512, pplWm3t);
    transpose_split3_w<<<dim3(16, 16), blk, 0, stream>>>(img_Wq, 1024, 1024, wq3t);
    transpose_split3_w<<<dim3(16, 16), blk, 0, stream>>>(ppl_Wq, 1024, 1024, wq3t + (size_t)1024 * 3072);

    // ---- precompute GEMMs ----
    // g_pre = relu(emb) @ visWih_demb^T + vis_b   [2560, 4096]
    gemm3<128, 128, false, true><<<dim3(32, 20), blk, 0, stream>>>(demb3, visdemb3, nullptr, vis_b, g_pre, G4, 1536);
    // pool attention
    gemm3<64, 64, false, false><<<dim3(8, 2), blk, 0, stream>>>(hint3, poolWq3t, nullptr, nullptr, pool_qW, 512, 1536);
    gemm3<128, 128, false, true><<<dim3(4, 36), blk, 0, stream>>>(img3, poolWm3t, nullptr, pool_b, pool_mW, 512, 1536);
    attn_score<<<dim3(NI, B), blk, 0, stream>>>(pool_qW, 512, pool_mW, pool_v, pool_sc, NI, 512);
    attn_ctx<0><<<dim3(B), blk, 0, stream>>>(pool_sc, img_feats, nullptr, imgpool3, NI);
    // g_const = img_pool @ visWih_pool^T ; broadcast into g_pre
    gemm3<64, 64, false, false><<<dim3(64, 2), blk, 0, stream>>>(imgpool3, vispool3, nullptr, nullptr, g_const, G4, 1536);
    add_bcast<<<dim3(T * B * G4 / 4 / 256), blk, 0, stream>>>(g_pre, g_const);
    // attention memories (+bias folded)
    gemm3<128, 128, false, true><<<dim3(8, 36), blk, 0, stream>>>(img3, imgWm3t, nullptr, img_b, img_mW, H, 1536);
    gemm3<128, 128, false, true><<<dim3(8, 100), blk, 0, stream>>>(ppl3, pplWm3t, nullptr, ppl_b, ppl_mW, H, 1536);

    // ---- sequential decode ----
    for (int t = 0; t < T; ++t) {
        gemm3<64, 64, true, false><<<dim3(64, 2), blk, 0, stream>>>(
            a3, visWhh3, g_pre + (size_t)t * B * G4, nullptr, gates, G4, 3072);
        lstm_vis<<<dim3(B * H / 256), blk, 0, stream>>>(gates, c_vis, a3, x3);
        gemm3<64, 64, false, false><<<dim3(32, 2), blk, 0, stream>>>(
            a3, wq3t, nullptr, nullptr, qbuf, 2048, 3072);
        attn_score<<<dim3(NI, B), blk, 0, stream>>>(qbuf, 2048, img_mW, img_v, score, NI, H);
        attn_ctx<1><<<dim3(B), blk, 0, stream>>>(score, img_feats, attn_buf, nullptr, NI);
        attn_score<<<dim3(NP, B), blk, 0, stream>>>(qbuf + 1024, 2048, ppl_mW, ppl_v, score, NP, H);
        attn_ctx<2><<<dim3(B), blk, 0, stream>>>(score, ppl_feats, attn_buf, x3, NP);
        gemm3<64, 64, false, true><<<dim3(64, 2), blk, 0, stream>>>(
            x3, langW3, nullptr, lang_b, gates, G4, 7680);
        lstm_lang<<<dim3(B * H / 256), blk, 0, stream>>>(gates, c_lang, x3, h3_all, t);
    }

    // ---- deferred projection (weight split overlaid on dead region X) ----
    transpose_split3_w<<<dim3(313, 16), blk, 0, stream>>>(proj_W, V, 1024, projW3t);
    gemm3<128, 128, false, true><<<dim3(157, 20), blk, 0, stream>>>(
        h3_all, projW3t, nullptr, proj_b, out, V, 3072);
    logsm_argmax<<<dim3(B * T), blk, 0, stream>>>(out);
}